// Round 1
// baseline (155.236 us; speedup 1.0000x reference)
//
#include <hip/hip_runtime.h>

// R9: one wave per ROW (grid 4096 x 64, single-wave WGs).
// Theory: R8 (~40us) was latency-bound at 2 waves/SIMD with an ~L-iteration
// serial token loop and a divergence-serialized tail. Changes:
//  - 4096 waves = 4 waves/SIMD (2x TLP); 16 x 1-wave WGs/CU, LDS ~1.2KB/WG
//  - token loop split even/odd across half-waves -> ceil(L/2) iterations,
//    combined with one shfl_xor(32)
//  - cont features read directly from global (L1 broadcast stream): no LDS
//    staging phase, no staging barrier
//  - tail de-divergenced: one unified emb-table loop (p-side: job+rep,
//    c-side: place+add) and one unified 32x32 second-layer loop via
//    per-half base pointers
// Algebra unchanged from R3-R8: histogram-weighted table sums, binary-vocab
// counts = index sums, pooling commutes with the 32x32 second layers.

#define BDIM 64

__global__ __launch_bounds__(BDIM, 4)
void mlpreg_kernel(const float* __restrict__ cont_p,
                   const float* __restrict__ cont_c,
                   const int* __restrict__ cat_p,
                   const int* __restrict__ cat_c,
                   const int* __restrict__ lengths,
                   const float* __restrict__ w_p1, const float* __restrict__ b_p1,
                   const float* __restrict__ w_p2, const float* __restrict__ b_p2,
                   const float* __restrict__ w_c1, const float* __restrict__ b_c1,
                   const float* __restrict__ w_c2, const float* __restrict__ b_c2,
                   const float* __restrict__ emb_g,  const float* __restrict__ emb_k,
                   const float* __restrict__ emb_pr, const float* __restrict__ emb_j,
                   const float* __restrict__ emb_r,  const float* __restrict__ emb_pl,
                   const float* __restrict__ emb_a,
                   const float* __restrict__ w_fc1, const float* __restrict__ b_fc1,
                   const float* __restrict__ w_fc2, const float* __restrict__ b_fc2,
                   float* __restrict__ out)
{
    constexpr int S = 256;
    __shared__ int   hist[96];    // job@0(11) rep@11(34) place@45(19) add@64(31)
    __shared__ float sAcc[64];    // [aP(32), aC(32)] pooled relu-layer1
    __shared__ float sPool[128];  // [ep, ec, hp, hc]

    const int lane = threadIdx.x;
    const int b = blockIdx.x;
    const int ch = lane & 31, h = lane >> 5;

    int L = lengths[b]; L = (L < 1) ? 1 : (L > S ? S : L);
    const float Lf = (float)L, invL = 1.0f / Lf;

    // zero hist (same-wave LDS ordering protects the later atomics)
    hist[lane] = 0;
    if (lane < 32) hist[64 + lane] = 0;

    // first-layer weights, one channel per lane (broadcast within halves)
    const float wp0 = w_p1[ch], wp1 = w_p1[32 + ch], wp2 = w_p1[64 + ch], bp = b_p1[ch];
    const float wc0 = w_c1[ch], wc1 = w_c1[32 + ch], bc = b_c1[ch];

    // ---- categorical pass: whole tokens per lane, strided 64 ----
    int sg = 0, sk = 0, sp = 0;
    {
        const int*  kp = cat_p + (size_t)b * (S * 5);
        const int2* kc = (const int2*)(cat_c + (size_t)b * (S * 2));
        #pragma unroll 2
        for (int t = lane; t < L; t += 64) {
            int v0 = kp[5 * t], v1 = kp[5 * t + 1], v2 = kp[5 * t + 2],
                v3 = kp[5 * t + 3], v4 = kp[5 * t + 4];
            int2 q = kc[t];
            sg += v0; sk += v1; sp += v2;
            atomicAdd(&hist[v3], 1);
            atomicAdd(&hist[11 + v4], 1);
            atomicAdd(&hist[45 + q.x], 1);
            atomicAdd(&hist[64 + q.y], 1);
        }
    }

    // ---- token relu-MLP: even/odd tokens split across half-waves,
    //      direct global broadcast reads (no LDS staging) ----
    float aP = 0.f, aC = 0.f;
    {
        const float* tp = cont_p + (size_t)b * (S * 3);
        const float* tc = cont_c + (size_t)b * (S * 2);
        #pragma unroll 4
        for (int t = h; t < L; t += 2) {
            float c0 = tp[3 * t], c1 = tp[3 * t + 1], c2 = tp[3 * t + 2];
            float2 d2 = *(const float2*)&tc[2 * t];
            aP += fmaxf(fmaf(c0, wp0, fmaf(c1, wp1, fmaf(c2, wp2, bp))), 0.f);
            aC += fmaxf(fmaf(d2.x, wc0, fmaf(d2.y, wc1, bc)), 0.f);
        }
    }
    aP += __shfl_xor(aP, 32);      // combine even/odd partial sums
    aC += __shfl_xor(aC, 32);
    #pragma unroll
    for (int d = 32; d; d >>= 1) {
        sg += __shfl_xor(sg, d); sk += __shfl_xor(sk, d); sp += __shfl_xor(sp, d);
    }

    sAcc[lane] = (h ? aC : aP) * invL;
    __syncthreads();   // B1 (1-wave WG: lgkmcnt drain, trivial barrier)

    // ---- tail, unified across halves (no divergent serialization) ----
    float A;
    {
        // binary-vocab closed form; computed by all lanes, h=1 discards
        float fg = (float)sg, fk = (float)sk, fp = (float)sp;
        float g0 = emb_g[ch],  g1 = emb_g[32 + ch];
        float k0 = emb_k[ch],  k1 = emb_k[32 + ch];
        float p0 = emb_pr[ch], p1 = emb_pr[32 + ch];
        A = fmaf(Lf - fg, g0, fg * g1) + fmaf(Lf - fk, k0, fk * k1)
          + fmaf(Lf - fp, p0, fp * p1);
        A = h ? 0.f : A;
    }
    {
        // p-side (h=0): job(11) then rep(34) over hist[0..44]
        // c-side (h=1): place(19) then add(31) over hist[45..94]
        const float* tA = h ? emb_pl : emb_j;
        const float* tB = h ? emb_a  : emb_r;
        const int nA = h ? 19 : 11;
        const int nT = h ? 50 : 45;   // per-half trip count (uniform per half)
        const int hb = h ? 45 : 0;
        #pragma unroll 5
        for (int r = 0; r < nT; ++r) {
            const float* p = (r < nA) ? (tA + (r << 5)) : (tB + ((r - nA) << 5));
            A = fmaf((float)hist[hb + r], p[ch], A);
        }
        sPool[(h << 5) + ch] = A * (invL * (h ? 0.5f : 0.2f));
    }
    {
        // unified 32x32 second layer: h=0 -> w_p2 on aP, h=1 -> w_c2 on aC
        const float* W2 = h ? w_c2 : w_p2;
        float v = (h ? b_c2 : b_p2)[ch];
        const float* acc = &sAcc[h << 5];
        #pragma unroll 8
        for (int k = 0; k < 32; ++k)
            v = fmaf(acc[k], W2[(k << 5) + ch], v);
        sPool[64 + (h << 5) + ch] = v;
    }
    __syncthreads();   // B2: sPool ready

    // ---- fc1 (one output per lane) + fc2 butterfly ----
    {
        float x = b_fc1[lane], y = 0.f;
        #pragma unroll 8
        for (int k = 0; k < 128; k += 4) {
            float4 u = *(const float4*)&sPool[k];
            float w0 = w_fc1[(size_t)(k    ) * 64 + lane];
            float w1 = w_fc1[(size_t)(k + 1) * 64 + lane];
            float w2 = w_fc1[(size_t)(k + 2) * 64 + lane];
            float w3 = w_fc1[(size_t)(k + 3) * 64 + lane];
            x = fmaf(u.x, w0, x); y = fmaf(u.y, w1, y);
            x = fmaf(u.z, w2, x); y = fmaf(u.w, w3, y);
        }
        float hv = fmaxf(x + y, 0.f);
        float q0 = hv * w_fc2[2 * lane], q1 = hv * w_fc2[2 * lane + 1];
        #pragma unroll
        for (int d = 32; d; d >>= 1) {
            q0 += __shfl_xor(q0, d); q1 += __shfl_xor(q1, d);
        }
        if (lane == 0) {
            float2 o2;
            o2.x = fmaxf(q0 + b_fc2[0], 0.f);
            o2.y = fmaxf(q1 + b_fc2[1], 0.f);
            *(float2*)&out[(size_t)b * 2] = o2;   // 8B-aligned per-row store
        }
    }
}

extern "C" void kernel_launch(void* const* d_in, const int* in_sizes, int n_in,
                              void* d_out, int out_size, void* d_ws, size_t ws_size,
                              hipStream_t stream) {
    const float* cont_p = (const float*)d_in[0];
    const float* cont_c = (const float*)d_in[1];
    const int*   cat_p  = (const int*)d_in[2];
    const int*   cat_c  = (const int*)d_in[3];
    const int*   lens   = (const int*)d_in[4];
    const float* w_p1   = (const float*)d_in[5];
    const float* b_p1   = (const float*)d_in[6];
    const float* w_p2   = (const float*)d_in[7];
    const float* b_p2   = (const float*)d_in[8];
    const float* w_c1   = (const float*)d_in[9];
    const float* b_c1   = (const float*)d_in[10];
    const float* w_c2   = (const float*)d_in[11];
    const float* b_c2   = (const float*)d_in[12];
    const float* emb_g  = (const float*)d_in[13];
    const float* emb_k  = (const float*)d_in[14];
    const float* emb_pr = (const float*)d_in[15];
    const float* emb_j  = (const float*)d_in[16];
    const float* emb_r  = (const float*)d_in[17];
    const float* emb_pl = (const float*)d_in[18];
    const float* emb_a  = (const float*)d_in[19];
    const float* w_fc1  = (const float*)d_in[20];
    const float* b_fc1  = (const float*)d_in[21];
    const float* w_fc2  = (const float*)d_in[22];
    const float* b_fc2  = (const float*)d_in[23];
    float* out = (float*)d_out;

    hipLaunchKernelGGL(mlpreg_kernel, dim3(4096), dim3(BDIM), 0, stream,
                       cont_p, cont_c, cat_p, cat_c, lens,
                       w_p1, b_p1, w_p2, b_p2, w_c1, b_c1, w_c2, b_c2,
                       emb_g, emb_k, emb_pr, emb_j, emb_r, emb_pl, emb_a,
                       w_fc1, b_fc1, w_fc2, b_fc2, out);
}

// Round 2
// 154.254 us; speedup vs baseline: 1.0064x; 1.0064x over previous
//
#include <hip/hip_runtime.h>

// R10: 8 rows per 512-thread WG (8 waves, one wave per row), grid 512.
// Theory: R8->R9 invariance (42us both) shows token loop + TLP aren't the
// pin; the constant was the per-row tail of ~210 broadcast GLOBAL weight
// loads (emb 50 + w2 32 + fc1 128) whose ~50KB working set thrashes the
// 32KB L1 (16 concurrent waves/CU), so each row pays a serial chain of
// L2-latency loads, 4096 times. Fix: stage ALL weights ONCE per WG into
// LDS (65KB incl. per-row state -> 2 WGs/CU, 4 waves/SIMD) and run the
// tail entirely from LDS with bank-clean layouts ([r*32+ch], [k*64+lane]).
// Weight traffic 200MB -> 27MB; per-row tail chain: VMEM -> LDS.
// Algebra unchanged from R3-R9: histogram-weighted table sums, binary-vocab
// counts = index sums, pooling commutes with the 32x32 second layers.

#define BDIM 512

__global__ __launch_bounds__(BDIM, 4)
void mlpreg_kernel(const float* __restrict__ cont_p,
                   const float* __restrict__ cont_c,
                   const int* __restrict__ cat_p,
                   const int* __restrict__ cat_c,
                   const int* __restrict__ lengths,
                   const float* __restrict__ w_p1, const float* __restrict__ b_p1,
                   const float* __restrict__ w_p2, const float* __restrict__ b_p2,
                   const float* __restrict__ w_c1, const float* __restrict__ b_c1,
                   const float* __restrict__ w_c2, const float* __restrict__ b_c2,
                   const float* __restrict__ emb_g,  const float* __restrict__ emb_k,
                   const float* __restrict__ emb_pr, const float* __restrict__ emb_j,
                   const float* __restrict__ emb_r,  const float* __restrict__ emb_pl,
                   const float* __restrict__ emb_a,
                   const float* __restrict__ w_fc1, const float* __restrict__ b_fc1,
                   const float* __restrict__ w_fc2, const float* __restrict__ b_fc2,
                   float* __restrict__ out)
{
    constexpr int S = 256;
    // ---- weights, staged once per WG ----
    __shared__ float sWfc1[128 * 64];   // 32768 B, [k*64+o]
    __shared__ float sWp2[32 * 32];     //  4096 B, [k*32+ch]
    __shared__ float sWc2[32 * 32];     //  4096 B
    __shared__ float sEmbT[95 * 32];    // 12160 B: job@0 rep@11 place@45 add@64 (matches hist)
    __shared__ float sEgkp[192];        //   768 B: g[0..63] k[64..127] pr[128..191]
    __shared__ float sWp1[96], sBp1[32], sWc1[64], sBc1[32], sBp2[32], sBc2[32];
    __shared__ float sBfc1[64], sWfc2[128], sBfc2[2];
    // ---- per-row state (8 rows) ----
    __shared__ int   hist[8][96];       //  3072 B
    __shared__ float sAcc[8][64];       //  2048 B
    __shared__ float sPool[8][128];     //  4096 B
    // total 65032 B -> 2 WGs/CU

    const int tid  = threadIdx.x;
    const int wid  = tid >> 6;
    const int lane = tid & 63;
    const int ch   = lane & 31, h = lane >> 5;

    // ---- phase 0: cooperative weight staging (coalesced float4) ----
    {
        const float4* g = (const float4*)w_fc1;
        float4* d = (float4*)sWfc1;
        #pragma unroll
        for (int i = tid; i < 2048; i += BDIM) d[i] = g[i];
        for (int i = tid; i < 256; i += BDIM) ((float4*)sWp2)[i] = ((const float4*)w_p2)[i];
        for (int i = tid; i < 256; i += BDIM) ((float4*)sWc2)[i] = ((const float4*)w_c2)[i];
        float4* e = (float4*)sEmbT;
        g = (const float4*)emb_j;
        for (int i = tid; i < 88;  i += BDIM) e[i]       = g[i];
        g = (const float4*)emb_r;
        for (int i = tid; i < 272; i += BDIM) e[88 + i]  = g[i];
        g = (const float4*)emb_pl;
        for (int i = tid; i < 152; i += BDIM) e[360 + i] = g[i];
        g = (const float4*)emb_a;
        for (int i = tid; i < 248; i += BDIM) e[512 + i] = g[i];
        if (tid < 64) {
            sEgkp[tid]       = emb_g[tid];
            sEgkp[64 + tid]  = emb_k[tid];
            sEgkp[128 + tid] = emb_pr[tid];
            sWc1[tid]  = w_c1[tid];
            sBfc1[tid] = b_fc1[tid];
        }
        if (tid < 96)  sWp1[tid]  = w_p1[tid];
        if (tid < 128) sWfc2[tid] = w_fc2[tid];
        if (tid < 32) {
            sBp1[tid] = b_p1[tid]; sBc1[tid] = b_c1[tid];
            sBp2[tid] = b_p2[tid]; sBc2[tid] = b_c2[tid];
        }
        if (tid < 2) sBfc2[tid] = b_fc2[tid];
    }
    // zero own row's hist (atomics happen after the barrier -> safe)
    hist[wid][lane] = 0;
    if (lane < 32) hist[wid][64 + lane] = 0;
    __syncthreads();   // B0: weights + hist ready

    const int b = blockIdx.x * 8 + wid;
    int L = lengths[b]; L = (L < 1) ? 1 : (L > S ? S : L);
    const float Lf = (float)L, invL = 1.0f / Lf;

    // first-layer weights from LDS (broadcast within halves)
    const float wp0 = sWp1[ch], wp1 = sWp1[32 + ch], wp2 = sWp1[64 + ch], bp = sBp1[ch];
    const float wc0 = sWc1[ch], wc1 = sWc1[32 + ch], bc = sBc1[ch];

    // ---- categorical pass: whole tokens per lane, strided 64 ----
    int sg = 0, sk = 0, sp = 0;
    {
        const int*  kp = cat_p + (size_t)b * (S * 5);
        const int2* kc = (const int2*)(cat_c + (size_t)b * (S * 2));
        #pragma unroll 2
        for (int t = lane; t < L; t += 64) {
            int v0 = kp[5 * t], v1 = kp[5 * t + 1], v2 = kp[5 * t + 2],
                v3 = kp[5 * t + 3], v4 = kp[5 * t + 4];
            int2 q = kc[t];
            sg += v0; sk += v1; sp += v2;
            atomicAdd(&hist[wid][v3], 1);
            atomicAdd(&hist[wid][11 + v4], 1);
            atomicAdd(&hist[wid][45 + q.x], 1);
            atomicAdd(&hist[wid][64 + q.y], 1);
        }
    }

    // ---- token relu-MLP: even/odd split across half-waves, global reads ----
    float aP = 0.f, aC = 0.f;
    {
        const float* tp = cont_p + (size_t)b * (S * 3);
        const float* tc = cont_c + (size_t)b * (S * 2);
        #pragma unroll 4
        for (int t = h; t < L; t += 2) {
            float c0 = tp[3 * t], c1 = tp[3 * t + 1], c2 = tp[3 * t + 2];
            float2 d2 = *(const float2*)&tc[2 * t];
            aP += fmaxf(fmaf(c0, wp0, fmaf(c1, wp1, fmaf(c2, wp2, bp))), 0.f);
            aC += fmaxf(fmaf(d2.x, wc0, fmaf(d2.y, wc1, bc)), 0.f);
        }
    }
    aP += __shfl_xor(aP, 32);
    aC += __shfl_xor(aC, 32);
    #pragma unroll
    for (int d = 32; d; d >>= 1) {
        sg += __shfl_xor(sg, d); sk += __shfl_xor(sk, d); sp += __shfl_xor(sp, d);
    }
    sAcc[wid][lane] = (h ? aC : aP) * invL;
    __syncthreads();   // B1: hist + sAcc ready

    // ---- tail, unified across halves, all weights from LDS ----
    float A;
    {
        float fg = (float)sg, fk = (float)sk, fp = (float)sp;
        float g0 = sEgkp[ch],       g1 = sEgkp[32 + ch];
        float k0 = sEgkp[64 + ch],  k1 = sEgkp[96 + ch];
        float p0 = sEgkp[128 + ch], p1 = sEgkp[160 + ch];
        A = fmaf(Lf - fg, g0, fg * g1) + fmaf(Lf - fk, k0, fk * k1)
          + fmaf(Lf - fp, p0, fp * p1);
        A = h ? 0.f : A;
    }
    {
        // p-side (h=0): hist[0..44] * sEmbT rows 0..44 (job+rep)
        // c-side (h=1): hist[45..94] * sEmbT rows 45..94 (place+add)
        const int nT = h ? 50 : 45;
        const int hb = h ? 45 : 0;
        const int* hrow = hist[wid];
        #pragma unroll 5
        for (int r = 0; r < nT; ++r)
            A = fmaf((float)hrow[hb + r], sEmbT[(hb + r) * 32 + ch], A);
        sPool[wid][(h << 5) + ch] = A * (invL * (h ? 0.5f : 0.2f));
    }
    {
        const float* W2 = h ? sWc2 : sWp2;
        float v = h ? sBc2[ch] : sBp2[ch];
        const float* acc = &sAcc[wid][h << 5];
        #pragma unroll 8
        for (int k = 0; k < 32; ++k)
            v = fmaf(acc[k], W2[(k << 5) + ch], v);
        sPool[wid][64 + (h << 5) + ch] = v;
    }
    __syncthreads();   // B2: sPool ready

    // ---- fc1 (one output per lane) + fc2 butterfly, all from LDS ----
    {
        float x = sBfc1[lane], y = 0.f;
        #pragma unroll 8
        for (int k = 0; k < 128; k += 2) {
            float2 u = *(const float2*)&sPool[wid][k];
            x = fmaf(u.x, sWfc1[k * 64 + lane], x);
            y = fmaf(u.y, sWfc1[(k + 1) * 64 + lane], y);
        }
        float hv = fmaxf(x + y, 0.f);
        float q0 = hv * sWfc2[2 * lane], q1 = hv * sWfc2[2 * lane + 1];
        #pragma unroll
        for (int d = 32; d; d >>= 1) {
            q0 += __shfl_xor(q0, d); q1 += __shfl_xor(q1, d);
        }
        if (lane == 0) {
            float2 o2;
            o2.x = fmaxf(q0 + sBfc2[0], 0.f);
            o2.y = fmaxf(q1 + sBfc2[1], 0.f);
            *(float2*)&out[(size_t)b * 2] = o2;
        }
    }
}

extern "C" void kernel_launch(void* const* d_in, const int* in_sizes, int n_in,
                              void* d_out, int out_size, void* d_ws, size_t ws_size,
                              hipStream_t stream) {
    const float* cont_p = (const float*)d_in[0];
    const float* cont_c = (const float*)d_in[1];
    const int*   cat_p  = (const int*)d_in[2];
    const int*   cat_c  = (const int*)d_in[3];
    const int*   lens   = (const int*)d_in[4];
    const float* w_p1   = (const float*)d_in[5];
    const float* b_p1   = (const float*)d_in[6];
    const float* w_p2   = (const float*)d_in[7];
    const float* b_p2   = (const float*)d_in[8];
    const float* w_c1   = (const float*)d_in[9];
    const float* b_c1   = (const float*)d_in[10];
    const float* w_c2   = (const float*)d_in[11];
    const float* b_c2   = (const float*)d_in[12];
    const float* emb_g  = (const float*)d_in[13];
    const float* emb_k  = (const float*)d_in[14];
    const float* emb_pr = (const float*)d_in[15];
    const float* emb_j  = (const float*)d_in[16];
    const float* emb_r  = (const float*)d_in[17];
    const float* emb_pl = (const float*)d_in[18];
    const float* emb_a  = (const float*)d_in[19];
    const float* w_fc1  = (const float*)d_in[20];
    const float* b_fc1  = (const float*)d_in[21];
    const float* w_fc2  = (const float*)d_in[22];
    const float* b_fc2  = (const float*)d_in[23];
    float* out = (float*)d_out;

    hipLaunchKernelGGL(mlpreg_kernel, dim3(512), dim3(BDIM), 0, stream,
                       cont_p, cont_c, cat_p, cat_c, lens,
                       w_p1, b_p1, w_p2, b_p2, w_c1, b_c1, w_c2, b_c2,
                       emb_g, emb_k, emb_pr, emb_j, emb_r, emb_pl, emb_a,
                       w_fc1, b_fc1, w_fc2, b_fc2, out);
}

// Round 4
// 143.211 us; speedup vs baseline: 1.0840x; 1.0771x over previous
//
#include <hip/hip_runtime.h>

// R11b: resubmit of R11 (infra failure last round, kernel audited clean).
// 16 rows per 512-thread WG (2 rows per wave, half-wave per row),
// grid 256 = exactly 1 WG/CU -> ALL 4096 rows resident in one generation.
// Theory: R8/R9/R10 all pinned at ~42us because each had a ~100-500-deep
// per-row chain of shallow-pipelined global loads at L3-cold latency (the
// 268MB harness fill evicts Infinity Cache every iteration). Kernel time =
// worst row's critical path. Fix: per-row global loads cut from ~540 scalar
// broadcasts to ~15 wide float4 bursts (cont staged L-aware to LDS by the
// owning wave; w_fc1 staged once per WG; token loop + fc1 from LDS).
// hist aliased into sPool region (all hist reads precede pool writes,
// same-wave lockstep ordered) -> LDS 126,976 B (static 128KiB verified on
// gfx950 per learn_hip m201). Tail unified (p/c across halves) AND
// dual-row (one weight load -> 2 FMAs); emb/w2 (20KB shared read-only)
// from global/L1; small weights in registers. One barrier total.
// Only change vs R11: __launch_bounds__ 2nd arg 2 -> 1 (2 was unreachable
// at 124KiB LDS and only constrained the register allocator).

#define BDIM 512

__global__ __launch_bounds__(BDIM, 1)
void mlpreg_kernel(const float* __restrict__ cont_p,
                   const float* __restrict__ cont_c,
                   const int* __restrict__ cat_p,
                   const int* __restrict__ cat_c,
                   const int* __restrict__ lengths,
                   const float* __restrict__ w_p1, const float* __restrict__ b_p1,
                   const float* __restrict__ w_p2, const float* __restrict__ b_p2,
                   const float* __restrict__ w_c1, const float* __restrict__ b_c1,
                   const float* __restrict__ w_c2, const float* __restrict__ b_c2,
                   const float* __restrict__ emb_g,  const float* __restrict__ emb_k,
                   const float* __restrict__ emb_pr, const float* __restrict__ emb_j,
                   const float* __restrict__ emb_r,  const float* __restrict__ emb_pl,
                   const float* __restrict__ emb_a,
                   const float* __restrict__ w_fc1, const float* __restrict__ b_fc1,
                   const float* __restrict__ w_fc2, const float* __restrict__ b_fc2,
                   float* __restrict__ out)
{
    constexpr int S = 256;
    __shared__ float sPc[16 * 768];   // cont_p rows       49152 B
    __shared__ float sCc[16 * 512];   // cont_c rows       32768 B
    __shared__ float sW1[128 * 64];   // w_fc1 [k*64+o]    32768 B
    __shared__ float sAcc[16][64];    // pooled layer1      4096 B
    __shared__ float sPB[16 * 128];   // pool UNION hist    8192 B
    // total 126,976 B -> 1 WG/CU, 256 WGs all resident

    const int tid  = threadIdx.x;
    const int wid  = tid >> 6;
    const int lane = tid & 63;
    const int ch   = lane & 31, h = lane >> 5;
    const int lr0  = wid << 1;                       // local row pair
    const int b0   = blockIdx.x * 16 + lr0, b1 = b0 + 1;

    // ---- register preloads: issue now, used much later ----
    int L0 = lengths[b0]; L0 = (L0 < 1) ? 1 : (L0 > S ? S : L0);
    int L1 = lengths[b1]; L1 = (L1 < 1) ? 1 : (L1 > S ? S : L1);
    const float L0f = (float)L0, L1f = (float)L1;
    const float invL0 = 1.0f / L0f, invL1 = 1.0f / L1f;

    const float wp0 = w_p1[ch], wp1 = w_p1[32 + ch], wp2 = w_p1[64 + ch], bp = b_p1[ch];
    const float wc0 = w_c1[ch], wc1 = w_c1[32 + ch], bc = b_c1[ch];
    const float eg0 = emb_g[ch],  eg1 = emb_g[32 + ch];
    const float ek0 = emb_k[ch],  ek1 = emb_k[32 + ch];
    const float er0 = emb_pr[ch], er1 = emb_pr[32 + ch];
    const float bias2 = h ? b_c2[ch] : b_p2[ch];
    const float bf1 = b_fc1[lane];
    const float2 wf2 = *(const float2*)&w_fc2[2 * lane];
    const float bq0 = b_fc2[0], bq1 = b_fc2[1];

    // ---- own-wave cont staging: L-aware float4 bursts ----
    {
        const float4* gp0 = (const float4*)(cont_p + (size_t)b0 * 768);
        const float4* gp1 = (const float4*)(cont_p + (size_t)b1 * 768);
        const float4* gc0 = (const float4*)(cont_c + (size_t)b0 * 512);
        const float4* gc1 = (const float4*)(cont_c + (size_t)b1 * 512);
        float4* dp0 = (float4*)(sPc + lr0 * 768);
        float4* dp1 = (float4*)(sPc + (lr0 + 1) * 768);
        float4* dc0 = (float4*)(sCc + lr0 * 512);
        float4* dc1 = (float4*)(sCc + (lr0 + 1) * 512);
        const int n0 = (3 * L0 + 3) >> 2, n1 = (3 * L1 + 3) >> 2;  // <=192
        const int m0 = (L0 + 1) >> 1,     m1 = (L1 + 1) >> 1;      // <=128
        for (int i = lane; i < n0; i += 64) dp0[i] = gp0[i];
        for (int i = lane; i < n1; i += 64) dp1[i] = gp1[i];
        for (int i = lane; i < m0; i += 64) dc0[i] = gc0[i];
        for (int i = lane; i < m1; i += 64) dc1[i] = gc1[i];
    }
    // ---- WG-cooperative w_fc1 staging (contiguous float4 copy) ----
    {
        const float4* gw = (const float4*)w_fc1;
        float4* dw = (float4*)sW1;
        #pragma unroll
        for (int i = tid; i < 2048; i += BDIM) dw[i] = gw[i];
    }
    // ---- hist (aliased into sPB rows of this wave); zero then atomics ----
    int* hist0 = (int*)(sPB + lr0 * 128);
    int* hist1 = (int*)(sPB + (lr0 + 1) * 128);
    hist0[lane] = 0; hist1[lane] = 0;
    if (lane < 32) { hist0[64 + lane] = 0; hist1[64 + lane] = 0; }

    // ---- categorical pass (direct global; overlaps staging latency) ----
    int sg0 = 0, sk0 = 0, sp0 = 0, sg1 = 0, sk1 = 0, sp1 = 0;
    {
        const int*  kp0 = cat_p + (size_t)b0 * (S * 5);
        const int*  kp1 = cat_p + (size_t)b1 * (S * 5);
        const int2* kc0 = (const int2*)(cat_c + (size_t)b0 * (S * 2));
        const int2* kc1 = (const int2*)(cat_c + (size_t)b1 * (S * 2));
        #pragma unroll 2
        for (int t = lane; t < L0; t += 64) {
            int v0 = kp0[5 * t], v1 = kp0[5 * t + 1], v2 = kp0[5 * t + 2],
                v3 = kp0[5 * t + 3], v4 = kp0[5 * t + 4];
            int2 q = kc0[t];
            sg0 += v0; sk0 += v1; sp0 += v2;
            atomicAdd(&hist0[v3], 1);
            atomicAdd(&hist0[11 + v4], 1);
            atomicAdd(&hist0[45 + q.x], 1);
            atomicAdd(&hist0[64 + q.y], 1);
        }
        #pragma unroll 2
        for (int t = lane; t < L1; t += 64) {
            int v0 = kp1[5 * t], v1 = kp1[5 * t + 1], v2 = kp1[5 * t + 2],
                v3 = kp1[5 * t + 3], v4 = kp1[5 * t + 4];
            int2 q = kc1[t];
            sg1 += v0; sk1 += v1; sp1 += v2;
            atomicAdd(&hist1[v3], 1);
            atomicAdd(&hist1[11 + v4], 1);
            atomicAdd(&hist1[45 + q.x], 1);
            atomicAdd(&hist1[64 + q.y], 1);
        }
    }
    #pragma unroll
    for (int d = 32; d; d >>= 1) {
        sg0 += __shfl_xor(sg0, d); sk0 += __shfl_xor(sk0, d); sp0 += __shfl_xor(sp0, d);
        sg1 += __shfl_xor(sg1, d); sk1 += __shfl_xor(sk1, d); sp1 += __shfl_xor(sp1, d);
    }
    __syncthreads();   // single barrier: sW1 visible WG-wide, staging drained

    // ---- token relu-MLP: half-wave h owns row lr0+h, LDS broadcast reads ----
    {
        const int   lr   = lr0 + h;
        const int   Lr   = h ? L1 : L0;
        const float invr = h ? invL1 : invL0;
        const float* tp = sPc + lr * 768;
        const float* tc = sCc + lr * 512;
        float aP = 0.f, aC = 0.f;
        #pragma unroll 4
        for (int t = 0; t < Lr; ++t) {
            float c0 = tp[3 * t], c1 = tp[3 * t + 1], c2 = tp[3 * t + 2];
            float2 d2 = *(const float2*)&tc[2 * t];
            aP += fmaxf(fmaf(c0, wp0, fmaf(c1, wp1, fmaf(c2, wp2, bp))), 0.f);
            aC += fmaxf(fmaf(d2.x, wc0, fmaf(d2.y, wc1, bc)), 0.f);
        }
        sAcc[lr][ch]      = aP * invr;
        sAcc[lr][32 + ch] = aC * invr;
    }

    // ---- tail: unified halves (h=0 p-side, h=1 c-side), dual-row FMA ----
    float A0, A1;
    {
        float fg0 = (float)sg0, fk0 = (float)sk0, fp0 = (float)sp0;
        float fg1 = (float)sg1, fk1 = (float)sk1, fp1 = (float)sp1;
        A0 = fmaf(L0f - fg0, eg0, fg0 * eg1) + fmaf(L0f - fk0, ek0, fk0 * ek1)
           + fmaf(L0f - fp0, er0, fp0 * er1);
        A1 = fmaf(L1f - fg1, eg0, fg1 * eg1) + fmaf(L1f - fk1, ek0, fk1 * ek1)
           + fmaf(L1f - fp1, er0, fp1 * er1);
        if (h) { A0 = 0.f; A1 = 0.f; }
    }
    {
        // h=0: job(11)+rep(34) over hist[0..44]; h=1: place(19)+add(31) over hist[45..94]
        const float* tA = h ? emb_pl : emb_j;
        const float* tB = h ? emb_a  : emb_r;
        const int nA = h ? 19 : 11;
        const int nT = h ? 50 : 45;
        const int hb = h ? 45 : 0;
        #pragma unroll 5
        for (int r = 0; r < nT; ++r) {
            const float* p = (r < nA) ? (tA + (r << 5)) : (tB + ((r - nA) << 5));
            float w = p[ch];
            A0 = fmaf((float)hist0[hb + r], w, A0);
            A1 = fmaf((float)hist1[hb + r], w, A1);
        }
        // all hist reads complete (wave lockstep program order) before writes
        const float sc = h ? 0.5f : 0.2f;
        sPB[lr0 * 128 + (h << 5) + ch]       = A0 * (invL0 * sc);
        sPB[(lr0 + 1) * 128 + (h << 5) + ch] = A1 * (invL1 * sc);
    }
    {
        // unified 32x32 second layer, dual-row: one weight load -> 2 FMAs
        const float* W2 = h ? w_c2 : w_p2;
        const float* a0 = &sAcc[lr0][h << 5];
        const float* a1 = &sAcc[lr0 + 1][h << 5];
        float v0 = bias2, v1 = bias2;
        #pragma unroll 8
        for (int k = 0; k < 32; ++k) {
            float w = W2[(k << 5) + ch];
            v0 = fmaf(a0[k], w, v0);
            v1 = fmaf(a1[k], w, v1);
        }
        sPB[lr0 * 128 + 64 + (h << 5) + ch]       = v0;
        sPB[(lr0 + 1) * 128 + 64 + (h << 5) + ch] = v1;
    }

    // ---- fc1 (one output per lane, dual-row) + fc2 butterfly ----
    {
        const float* P0 = sPB + lr0 * 128;
        const float* P1 = P0 + 128;
        float x0 = bf1, y0 = 0.f, x1 = bf1, y1 = 0.f;
        #pragma unroll 8
        for (int k = 0; k < 128; k += 2) {
            float w0 = sW1[k * 64 + lane];
            float w1 = sW1[(k + 1) * 64 + lane];
            float2 u0 = *(const float2*)&P0[k];
            float2 u1 = *(const float2*)&P1[k];
            x0 = fmaf(u0.x, w0, x0); y0 = fmaf(u0.y, w1, y0);
            x1 = fmaf(u1.x, w0, x1); y1 = fmaf(u1.y, w1, y1);
        }
        float h0v = fmaxf(x0 + y0, 0.f);
        float h1v = fmaxf(x1 + y1, 0.f);
        float q00 = h0v * wf2.x, q01 = h0v * wf2.y;
        float q10 = h1v * wf2.x, q11 = h1v * wf2.y;
        #pragma unroll
        for (int d = 32; d; d >>= 1) {
            q00 += __shfl_xor(q00, d); q01 += __shfl_xor(q01, d);
            q10 += __shfl_xor(q10, d); q11 += __shfl_xor(q11, d);
        }
        if (lane == 0) {
            float4 o4;
            o4.x = fmaxf(q00 + bq0, 0.f);
            o4.y = fmaxf(q01 + bq1, 0.f);
            o4.z = fmaxf(q10 + bq0, 0.f);
            o4.w = fmaxf(q11 + bq1, 0.f);
            *(float4*)&out[(size_t)b0 * 2] = o4;   // rows b0,b1; 16B-aligned
        }
    }
}

extern "C" void kernel_launch(void* const* d_in, const int* in_sizes, int n_in,
                              void* d_out, int out_size, void* d_ws, size_t ws_size,
                              hipStream_t stream) {
    const float* cont_p = (const float*)d_in[0];
    const float* cont_c = (const float*)d_in[1];
    const int*   cat_p  = (const int*)d_in[2];
    const int*   cat_c  = (const int*)d_in[3];
    const int*   lens   = (const int*)d_in[4];
    const float* w_p1   = (const float*)d_in[5];
    const float* b_p1   = (const float*)d_in[6];
    const float* w_p2   = (const float*)d_in[7];
    const float* b_p2   = (const float*)d_in[8];
    const float* w_c1   = (const float*)d_in[9];
    const float* b_c1   = (const float*)d_in[10];
    const float* w_c2   = (const float*)d_in[11];
    const float* b_c2   = (const float*)d_in[12];
    const float* emb_g  = (const float*)d_in[13];
    const float* emb_k  = (const float*)d_in[14];
    const float* emb_pr = (const float*)d_in[15];
    const float* emb_j  = (const float*)d_in[16];
    const float* emb_r  = (const float*)d_in[17];
    const float* emb_pl = (const float*)d_in[18];
    const float* emb_a  = (const float*)d_in[19];
    const float* w_fc1  = (const float*)d_in[20];
    const float* b_fc1  = (const float*)d_in[21];
    const float* w_fc2  = (const float*)d_in[22];
    const float* b_fc2  = (const float*)d_in[23];
    float* out = (float*)d_out;

    hipLaunchKernelGGL(mlpreg_kernel, dim3(256), dim3(BDIM), 0, stream,
                       cont_p, cont_c, cat_p, cat_c, lens,
                       w_p1, b_p1, w_p2, b_p2, w_c1, b_c1, w_c2, b_c2,
                       emb_g, emb_k, emb_pr, emb_j, emb_r, emb_pl, emb_a,
                       w_fc1, b_fc1, w_fc2, b_fc2, out);
}